// Round 10
// baseline (35.995 us; speedup 1.0000x reference)
//
#include <hip/hip_runtime.h>

// Problem constants (fixed by the reference):
//   B=64, L=2048, D=1024, seq f32, begin/end int32 (harness downcasts int64),
//   out f32 [B, D]
#define B_ 64
#define L_ 2048
#define D_ 1024
#define D4 (D_ / 4)   // 256 float4 per row; one per thread
#define QR 8          // rows per ragged task (32 KB contiguous stream)
#define NB 512        // stage1 blocks: 2/CU, perfectly equalized task ranges
// Design (round 10): ragged rows are split into nt = sum(ceil(len_b/8)) tasks.
// Block k owns tasks [k*nt/NB, (k+1)*nt/NB) -> per-block work equal +-1 task;
// no reliance on HW scheduling for balance. Contiguous same-batch tasks are
// accumulated in registers and flushed ONCE per (block x batch) segment to
// ws[seg_head] pre-scaled by 1/len -> ws round-trip ~2.3 MB (vs 32 MB for
// SPLIT=64). Stage2 recomputes segment-head slots arithmetically: slot t is a
// head iff t==start_b or t is some block's range start. No atomics, no
// fences (round 8: per-block device fences cost ~80ns serialized = 330us).

__global__ __launch_bounds__(256) void seg_mean_stage1(
    const float* __restrict__ seq,
    const int* __restrict__ begin,
    const int* __restrict__ end,
    float* __restrict__ ws)
{
    const int k = blockIdx.x;

    // Total task count nt (begin/end: 512 B, L1-broadcast; ~64 cheap iters).
    int nt = 0;
    #pragma unroll
    for (int b = 0; b < B_; ++b) nt += (end[b] - begin[b] + QR - 1) / QR;

    const int tk0 = (int)(((long long)k * nt) / NB);
    const int tk1 = (int)(((long long)(k + 1) * nt) / NB);
    if (tk0 >= tk1) return;   // only possible if nt < NB (not for this data)

    // Find batch b containing task tk0; sb = first task id of batch b.
    int b = 0, sb = 0;
    for (;;) {
        int ns = (end[b] - begin[b] + QR - 1) / QR;
        if (sb + ns > tk0) break;
        sb += ns; ++b;
    }

    const int col = threadIdx.x;                 // float4 column 0..255
    const float4* __restrict__ s4 = reinterpret_cast<const float4*>(seq);
    float4* __restrict__ w4 = reinterpret_cast<float4*>(ws);

    int bg = begin[b], en = end[b], len = en - bg;
    int ns = (len + QR - 1) / QR;

    float4 a0 = make_float4(0.f, 0.f, 0.f, 0.f);
    float4 a1 = a0, a2 = a0, a3 = a0;
    int seg_head = tk0;

    for (int t = tk0; t < tk1; ++t) {
        int j = t - sb;
        if (j == ns) {
            // Batch boundary: flush current segment (pre-scaled by 1/len).
            const float inv = 1.0f / (float)len;
            float4 o;
            o.x = (a0.x + a1.x + a2.x + a3.x) * inv;
            o.y = (a0.y + a1.y + a2.y + a3.y) * inv;
            o.z = (a0.z + a1.z + a2.z + a3.z) * inv;
            o.w = (a0.w + a1.w + a2.w + a3.w) * inv;
            w4[(size_t)seg_head * D4 + col] = o;
            a0 = make_float4(0.f, 0.f, 0.f, 0.f);
            a1 = a0; a2 = a0; a3 = a0;
            seg_head = t;
            sb += ns; ++b;
            bg = begin[b]; en = end[b]; len = en - bg;
            ns = (len + QR - 1) / QR;
            j = 0;
        }
        // Accumulate rows [bg + j*QR, min(bg+(j+1)*QR, en)) of batch b.
        int l  = bg + j * QR;
        const int l1 = min(l + QR, en);
        const float4* __restrict__ base = s4 + (size_t)b * (L_ * D4);
        for (; l + 4 <= l1; l += 4) {            // 4 independent 16B loads
            float4 v0 = base[(size_t)(l + 0) * D4 + col];
            float4 v1 = base[(size_t)(l + 1) * D4 + col];
            float4 v2 = base[(size_t)(l + 2) * D4 + col];
            float4 v3 = base[(size_t)(l + 3) * D4 + col];
            a0.x += v0.x; a0.y += v0.y; a0.z += v0.z; a0.w += v0.w;
            a1.x += v1.x; a1.y += v1.y; a1.z += v1.z; a1.w += v1.w;
            a2.x += v2.x; a2.y += v2.y; a2.z += v2.z; a2.w += v2.w;
            a3.x += v3.x; a3.y += v3.y; a3.z += v3.z; a3.w += v3.w;
        }
        for (; l < l1; ++l) {
            float4 v = base[(size_t)l * D4 + col];
            a0.x += v.x; a0.y += v.y; a0.z += v.z; a0.w += v.w;
        }
    }
    // Final flush.
    const float inv = 1.0f / (float)len;
    float4 o;
    o.x = (a0.x + a1.x + a2.x + a3.x) * inv;
    o.y = (a0.y + a1.y + a2.y + a3.y) * inv;
    o.z = (a0.z + a1.z + a2.z + a3.z) * inv;
    o.w = (a0.w + a1.w + a2.w + a3.w) * inv;
    w4[(size_t)seg_head * D4 + col] = o;
}

// Stage 2: grid (B_, 4). Block (b,q) sums batch b's segment-head partials for
// float4 cols [q*64, (q+1)*64). Head predicate: t==start_b, or t is a block
// range start: ceil(t*NB/nt)*nt < t*NB + NB. Non-head slots are never read.
__global__ __launch_bounds__(256) void seg_mean_stage2(
    const float* __restrict__ ws,
    const int* __restrict__ begin,
    const int* __restrict__ end,
    float* __restrict__ out)
{
    const int b    = blockIdx.x;
    const int q    = blockIdx.y;
    const int lane = threadIdx.x & 63;
    const int sg   = threadIdx.x >> 6;       // 4 s-groups (one wave each)

    int nt = 0, sb = 0;
    #pragma unroll
    for (int bb = 0; bb < B_; ++bb) {
        int ns = (end[bb] - begin[bb] + QR - 1) / QR;
        if (bb < b) sb += ns;
        nt += ns;
    }
    const int ns_b = (end[b] - begin[b] + QR - 1) / QR;

    const float4* __restrict__ w4 = reinterpret_cast<const float4*>(ws);
    float4 acc = make_float4(0.f, 0.f, 0.f, 0.f);

    for (int t = sb + sg; t < sb + ns_b; t += 4) {
        bool head;
        if (t == sb) {
            head = true;
        } else {
            int c = (t * NB + nt - 1) / nt;  // ceil(t*NB/nt); fits int32
            head = (c * nt < t * NB + NB);   // some block starts at t
        }
        if (head) {
            float4 v = w4[(size_t)t * D4 + q * 64 + lane];
            acc.x += v.x; acc.y += v.y; acc.z += v.z; acc.w += v.w;
        }
    }

    __shared__ float4 red[256];
    red[threadIdx.x] = acc;
    __syncthreads();

    if (sg == 0) {
        float4 r0 = red[lane];
        float4 r1 = red[lane + 64];
        float4 r2 = red[lane + 128];
        float4 r3 = red[lane + 192];
        float4 t;
        t.x = (r0.x + r1.x) + (r2.x + r3.x);
        t.y = (r0.y + r1.y) + (r2.y + r3.y);
        t.z = (r0.z + r1.z) + (r2.z + r3.z);
        t.w = (r0.w + r1.w) + (r2.w + r3.w);
        reinterpret_cast<float4*>(out)[(size_t)b * D4 + q * 64 + lane] = t;
    }
}

extern "C" void kernel_launch(void* const* d_in, const int* in_sizes, int n_in,
                              void* d_out, int out_size, void* d_ws, size_t ws_size,
                              hipStream_t stream) {
    const float* seq   = (const float*)d_in[0];
    const int*   begin = (const int*)d_in[1];   // int32: harness downcasts jnp.int64
    const int*   end   = (const int*)d_in[2];
    float*       out   = (float*)d_out;
    float*       ws    = (float*)d_ws;          // <= 8192 tasks * 4 KB = 33.5 MB

    seg_mean_stage1<<<NB, 256, 0, stream>>>(seq, begin, end, ws);
    dim3 g2(B_, 4);
    seg_mean_stage2<<<g2, 256, 0, stream>>>(ws, begin, end, out);
}

// Round 11
// 31.726 us; speedup vs baseline: 1.1346x; 1.1346x over previous
//
#include <hip/hip_runtime.h>
#include <hip/hip_fp16.h>

// Problem constants (fixed by the reference):
//   B=64, L=2048, D=1024, seq f32, begin/end int32 (harness downcasts int64),
//   out f32 [B, D]
#define B_ 64
#define L_ 2048
#define D_ 1024
#define D4 (D_ / 4)
#define SPLIT 64   // slices per batch -> stage1 grid (64,64) = 4096 blocks
// Structure = round 6 exactly (best measured: 32.8us): grid (SPLIT, B_)
// de-aliases batch->CU (each CU serves ~16 distinct batches) + 2x
// oversubscription for dynamic balancing; quantum <= 16 rows.
// Round-11 change: ws partials stored as f16 (pre-scaled |p|<=16, f16 RNE
// err ~2^-11 rel -> accumulated ~1e-3 << 1.2e-2 threshold). Halves the
// serialized inter-kernel L2 writeback (16->8 MB) and stage2's cold read.
// No atomics, no fences (R8: per-block device fences = 330us disaster).

// Stage 1: block (s,b) accumulates rows [bg+s*per, min(bg+(s+1)*per,en)) of
// batch b, stores pre-scaled f16 partial (zeros if empty) to ws[b][s][:].
__global__ __launch_bounds__(256) void seg_mean_stage1(
    const float* __restrict__ seq,
    const int* __restrict__ begin,
    const int* __restrict__ end,
    float* __restrict__ ws)
{
    const int s  = blockIdx.x;
    const int b  = blockIdx.y;
    const int bg = begin[b];
    const int en = end[b];
    const int len = en - bg;             // >= 1

    const int per = (len + SPLIT - 1) / SPLIT;
    const int l0  = bg + s * per;
    const int l1  = min(l0 + per, en);   // may be empty -> stores zeros

    const int col = threadIdx.x;         // one float4 of the D=1024 row
    const float4* __restrict__ base =
        reinterpret_cast<const float4*>(seq + (size_t)b * L_ * D_);

    float4 a0 = make_float4(0.f, 0.f, 0.f, 0.f);
    float4 a1 = a0, a2 = a0, a3 = a0;

    int l = l0;
    for (; l + 4 <= l1; l += 4) {        // 4 independent 16B loads in flight
        float4 v0 = base[(size_t)(l + 0) * D4 + col];
        float4 v1 = base[(size_t)(l + 1) * D4 + col];
        float4 v2 = base[(size_t)(l + 2) * D4 + col];
        float4 v3 = base[(size_t)(l + 3) * D4 + col];
        a0.x += v0.x; a0.y += v0.y; a0.z += v0.z; a0.w += v0.w;
        a1.x += v1.x; a1.y += v1.y; a1.z += v1.z; a1.w += v1.w;
        a2.x += v2.x; a2.y += v2.y; a2.z += v2.z; a2.w += v2.w;
        a3.x += v3.x; a3.y += v3.y; a3.z += v3.z; a3.w += v3.w;
    }
    for (; l < l1; ++l) {
        float4 v = base[(size_t)l * D4 + col];
        a0.x += v.x; a0.y += v.y; a0.z += v.z; a0.w += v.w;
    }

    const float inv = 1.0f / (float)len; // pre-scale so stage2 is a plain sum
    float4 t;
    t.x = (a0.x + a1.x + a2.x + a3.x) * inv;
    t.y = (a0.y + a1.y + a2.y + a3.y) * inv;
    t.z = (a0.z + a1.z + a2.z + a3.z) * inv;
    t.w = (a0.w + a1.w + a2.w + a3.w) * inv;

    // Pack 4 floats -> 4 halfs (8 B) and store coalesced.
    union { __half2 h2[2]; float2 f2; } u;
    u.h2[0] = __floats2half2_rn(t.x, t.y);
    u.h2[1] = __floats2half2_rn(t.z, t.w);
    float2* __restrict__ w2 = reinterpret_cast<float2*>(ws);
    w2[((size_t)(b * SPLIT + s)) * D4 + col] = u.f2;   // unconditional
}

// Stage 2: block b, thread col sums ws[b][0..SPLIT)[col4] (f16 -> f32) and
// overwrites out. 64 blocks; each block reads 128 KB contiguous.
__global__ __launch_bounds__(256) void seg_mean_stage2(
    const float* __restrict__ ws,
    float* __restrict__ out)
{
    const int b   = blockIdx.x;
    const int col = threadIdx.x;
    const float2* __restrict__ w2 =
        reinterpret_cast<const float2*>(ws) + (size_t)b * SPLIT * D4;

    float4 acc = make_float4(0.f, 0.f, 0.f, 0.f);
    #pragma unroll 8
    for (int s = 0; s < SPLIT; ++s) {
        union { float2 f2; __half2 h2[2]; } u;
        u.f2 = w2[(size_t)s * D4 + col];
        float2 lo = __half22float2(u.h2[0]);
        float2 hi = __half22float2(u.h2[1]);
        acc.x += lo.x; acc.y += lo.y; acc.z += hi.x; acc.w += hi.y;
    }
    reinterpret_cast<float4*>(out)[(size_t)b * D4 + col] = acc;
}

extern "C" void kernel_launch(void* const* d_in, const int* in_sizes, int n_in,
                              void* d_out, int out_size, void* d_ws, size_t ws_size,
                              hipStream_t stream) {
    const float* seq   = (const float*)d_in[0];
    const int*   begin = (const int*)d_in[1];   // int32: harness downcasts jnp.int64
    const int*   end   = (const int*)d_in[2];
    float*       out   = (float*)d_out;
    float*       ws    = (float*)d_ws;          // needs 64*64*1024*2 = 8 MB

    dim3 g1(SPLIT, B_);                         // s fastest -> de-alias batch->CU
    seg_mean_stage1<<<g1, 256, 0, stream>>>(seq, begin, end, ws);
    seg_mean_stage2<<<B_, 256, 0, stream>>>(ws, out);
}

// Round 12
// 30.174 us; speedup vs baseline: 1.1929x; 1.0514x over previous
//
#include <hip/hip_runtime.h>
#include <hip/hip_fp16.h>

// Problem constants (fixed by the reference):
//   B=64, L=2048, D=1024, seq f32, begin/end int32 (harness downcasts int64),
//   out f32 [B, D]
#define B_ 64
#define L_ 2048
#define D_ 1024
#define D4 (D_ / 4)   // 256 float4 per row
#define CG 32         // column groups: 8 float4 = 128B stripe (one L2 line/row)
#define RS 2          // row slices per span
// Round-12 design: column-split ownership. Block (gc, b) with gc = g*2+r owns
// batch b, column group g (8 f4), row-half r. It streams len/2 rows x 128B,
// LDS-reduces to 8 float4, stores ONE 64B f16 partial -> ws round-trip is
// 256 KB total (vs 16 MB in R11). Stage2 sums the 2 row-halves (512 KB read).
// Grid (64, 64): linear id = gc + 64*b -> CU c serves b = c/64 + 4k: 16
// distinct batches/CU (R6 de-alias) + 2x oversubscription, quantum <= 64 KB.
// No atomics, no fences (R8: per-block device fences = 330 us disaster).

__global__ __launch_bounds__(256) void seg_mean_stage1(
    const float* __restrict__ seq,
    const int* __restrict__ begin,
    const int* __restrict__ end,
    __half* __restrict__ ws)
{
    const int gc = blockIdx.x;        // 0..63
    const int g  = gc >> 1;           // column group 0..31
    const int r  = gc & 1;            // row slice 0..1
    const int b  = blockIdx.y;

    const int bg  = begin[b];
    const int en  = end[b];
    const int len = en - bg;          // >= 1
    const int half = (len + 1) >> 1;
    const int l0 = (r == 0) ? bg : bg + half;
    const int l1 = (r == 0) ? bg + half : en;

    const int col8   = threadIdx.x & 7;    // f4 col within group
    const int rowoff = threadIdx.x >> 3;   // 0..31

    // f4 address of (row l): b*L*256 + l*256 + g*8 + col8
    const float4* __restrict__ base =
        reinterpret_cast<const float4*>(seq) + (size_t)b * (L_ * D4) + g * 8 + col8;

    float4 a0 = make_float4(0.f, 0.f, 0.f, 0.f);
    float4 a1 = a0, a2 = a0, a3 = a0;

    int l = l0 + rowoff;
    for (; l < l1 - 96; l += 128) {        // 4 independent 16B loads in flight
        float4 v0 = base[(size_t)(l +  0) * D4];
        float4 v1 = base[(size_t)(l + 32) * D4];
        float4 v2 = base[(size_t)(l + 64) * D4];
        float4 v3 = base[(size_t)(l + 96) * D4];
        a0.x += v0.x; a0.y += v0.y; a0.z += v0.z; a0.w += v0.w;
        a1.x += v1.x; a1.y += v1.y; a1.z += v1.z; a1.w += v1.w;
        a2.x += v2.x; a2.y += v2.y; a2.z += v2.z; a2.w += v2.w;
        a3.x += v3.x; a3.y += v3.y; a3.z += v3.z; a3.w += v3.w;
    }
    for (; l < l1; l += 32) {
        float4 v = base[(size_t)l * D4];
        a0.x += v.x; a0.y += v.y; a0.z += v.z; a0.w += v.w;
    }

    float4 acc;
    acc.x = (a0.x + a1.x) + (a2.x + a3.x);
    acc.y = (a0.y + a1.y) + (a2.y + a3.y);
    acc.z = (a0.z + a1.z) + (a2.z + a3.z);
    acc.w = (a0.w + a1.w) + (a2.w + a3.w);

    // Reduce the 32 row-slots per column (t & 7 preserved by strides >= 8).
    __shared__ float4 red[256];
    red[threadIdx.x] = acc;
    __syncthreads();
    #pragma unroll
    for (int s = 128; s >= 8; s >>= 1) {
        if (threadIdx.x < s) {
            float4 o = red[threadIdx.x + s];
            red[threadIdx.x].x += o.x;
            red[threadIdx.x].y += o.y;
            red[threadIdx.x].z += o.z;
            red[threadIdx.x].w += o.w;
        }
        __syncthreads();
    }

    if (threadIdx.x < 8) {
        float4 t = red[threadIdx.x];
        const float inv = 1.0f / (float)len;   // pre-scale: stage2 is a plain add
        union { __half2 h2[2]; float2 f2; } u;
        u.h2[0] = __floats2half2_rn(t.x * inv, t.y * inv);
        u.h2[1] = __floats2half2_rn(t.z * inv, t.w * inv);
        // slot = (b*CG + g)*RS + r ; 32 halfs (64B) per slot
        float2* __restrict__ w2 = reinterpret_cast<float2*>(ws);
        w2[(size_t)(((b * CG + g) * RS + r)) * 8 + threadIdx.x] = u.f2;
    }
}

// Stage 2: 256 blocks x 256 threads; one output float per thread.
// out[b][col] = ws[b][g][0][c] + ws[b][g][1][c]  (f16 -> f32).
__global__ __launch_bounds__(256) void seg_mean_stage2(
    const __half* __restrict__ ws,
    float* __restrict__ out)
{
    const int idx = blockIdx.x * 256 + threadIdx.x;   // 0..65535
    const int b   = idx >> 10;
    const int col = idx & 1023;
    const int g   = col >> 5;
    const int c   = col & 31;

    const size_t s0 = (size_t)((b * CG + g) * RS) * 32 + c;
    out[idx] = __half2float(ws[s0]) + __half2float(ws[s0 + 32]);
}

extern "C" void kernel_launch(void* const* d_in, const int* in_sizes, int n_in,
                              void* d_out, int out_size, void* d_ws, size_t ws_size,
                              hipStream_t stream) {
    const float* seq   = (const float*)d_in[0];
    const int*   begin = (const int*)d_in[1];   // int32: harness downcasts jnp.int64
    const int*   end   = (const int*)d_in[2];
    float*       out   = (float*)d_out;
    __half*      ws    = (__half*)d_ws;         // 64*32*2*32 halfs = 256 KB

    dim3 g1(CG * RS, B_);                       // gc fastest -> de-alias batch->CU
    seg_mean_stage1<<<g1, 256, 0, stream>>>(seq, begin, end, ws);
    seg_mean_stage2<<<B_ * D_ / 65536 * 256, 256, 0, stream>>>(ws, out);
}

// Round 14
// 28.081 us; speedup vs baseline: 1.2818x; 1.0745x over previous
//
#include <hip/hip_runtime.h>
#include <hip/hip_fp16.h>

// Problem constants (fixed by the reference):
//   B=64, L=2048, D=1024, seq f32, begin/end int32 (harness downcasts int64),
//   out f32 [B, D]
#define B_ 64
#define L_ 2048
#define D_ 1024
#define D4 (D_ / 4)   // 256 float4 per row
#define CG 32         // column groups: 8 float4 = 128B stripe
#define RS 4          // row slices per span (R14: testing finer quanta vs R12's 2)
// R12 structure (best: 30.2us) + finer row slicing. Block (gc, b), gc=g*4+r,
// owns batch b, column group g (128B stripe), row quarter r. Streams
// len/4 rows x 128B, LDS-reduces to 8 float4, flushes ONE 64B f16 partial.
// ws total = 8192 x 64B = 512 KB. Grid (128,64) = 8192 blocks = 4x
// oversubscription (quantum <= 32 KB) for dynamic tail balancing.
// No atomics, no fences (R8: per-block device fences = 330us disaster).
// R13 bug: stage2 grid arithmetic gave 1 block -> only 256 outputs written.
// Stage2 needs (B_*D_)/256 = 256 blocks of 256 threads.

__global__ __launch_bounds__(256) void seg_mean_stage1(
    const float* __restrict__ seq,
    const int* __restrict__ begin,
    const int* __restrict__ end,
    __half* __restrict__ ws)
{
    const int gc = blockIdx.x;        // 0..127
    const int g  = gc >> 2;           // column group 0..31
    const int r  = gc & 3;            // row quarter 0..3
    const int b  = blockIdx.y;

    const int bg  = begin[b];
    const int en  = end[b];
    const int len = en - bg;          // >= 1  (len <= 1023: len*r fits easily)
    const int l0  = bg + ((len * r) >> 2);
    const int l1  = bg + ((len * (r + 1)) >> 2);   // quarters tile [bg, en)

    const int col8   = threadIdx.x & 7;    // f4 col within group
    const int rowoff = threadIdx.x >> 3;   // 0..31

    // f4 address of row l: b*L*256 + l*256 + g*8 + col8
    const float4* __restrict__ base =
        reinterpret_cast<const float4*>(seq) + (size_t)b * (L_ * D4) + g * 8 + col8;

    float4 a0 = make_float4(0.f, 0.f, 0.f, 0.f);
    float4 a1 = a0, a2 = a0, a3 = a0;

    int l = l0 + rowoff;
    for (; l < l1 - 96; l += 128) {        // 4 independent 16B loads in flight
        float4 v0 = base[(size_t)(l +  0) * D4];
        float4 v1 = base[(size_t)(l + 32) * D4];
        float4 v2 = base[(size_t)(l + 64) * D4];
        float4 v3 = base[(size_t)(l + 96) * D4];
        a0.x += v0.x; a0.y += v0.y; a0.z += v0.z; a0.w += v0.w;
        a1.x += v1.x; a1.y += v1.y; a1.z += v1.z; a1.w += v1.w;
        a2.x += v2.x; a2.y += v2.y; a2.z += v2.z; a2.w += v2.w;
        a3.x += v3.x; a3.y += v3.y; a3.z += v3.z; a3.w += v3.w;
    }
    for (; l < l1; l += 32) {
        float4 v = base[(size_t)l * D4];
        a0.x += v.x; a0.y += v.y; a0.z += v.z; a0.w += v.w;
    }

    float4 acc;
    acc.x = (a0.x + a1.x) + (a2.x + a3.x);
    acc.y = (a0.y + a1.y) + (a2.y + a3.y);
    acc.z = (a0.z + a1.z) + (a2.z + a3.z);
    acc.w = (a0.w + a1.w) + (a2.w + a3.w);

    // Reduce the 32 row-slots per column (bit pattern t&7 preserved).
    __shared__ float4 red[256];
    red[threadIdx.x] = acc;
    __syncthreads();
    #pragma unroll
    for (int s = 128; s >= 8; s >>= 1) {
        if (threadIdx.x < s) {
            float4 o = red[threadIdx.x + s];
            red[threadIdx.x].x += o.x;
            red[threadIdx.x].y += o.y;
            red[threadIdx.x].z += o.z;
            red[threadIdx.x].w += o.w;
        }
        __syncthreads();
    }

    if (threadIdx.x < 8) {
        float4 t = red[threadIdx.x];
        const float inv = 1.0f / (float)len;   // pre-scale: stage2 is a plain add
        union { __half2 h2[2]; float2 f2; } u;
        u.h2[0] = __floats2half2_rn(t.x * inv, t.y * inv);
        u.h2[1] = __floats2half2_rn(t.z * inv, t.w * inv);
        // slot = (b*CG + g)*RS + r ; 32 halfs (64B) per slot
        float2* __restrict__ w2 = reinterpret_cast<float2*>(ws);
        w2[(size_t)(((b * CG + g) * RS + r)) * 8 + threadIdx.x] = u.f2;
    }
}

// Stage 2: 256 blocks x 256 threads; one output float per thread.
// out[b][col] = sum_r ws[b][g][r][c]  (f16 -> f32), r = 0..3.
__global__ __launch_bounds__(256) void seg_mean_stage2(
    const __half* __restrict__ ws,
    float* __restrict__ out)
{
    const int idx = blockIdx.x * 256 + threadIdx.x;   // 0..65535
    const int b   = idx >> 10;
    const int col = idx & 1023;
    const int g   = col >> 5;
    const int c   = col & 31;

    const size_t s0 = (size_t)((b * CG + g) * RS) * 32 + c;
    out[idx] = (__half2float(ws[s0])      + __half2float(ws[s0 + 32]))
             + (__half2float(ws[s0 + 64]) + __half2float(ws[s0 + 96]));
}

extern "C" void kernel_launch(void* const* d_in, const int* in_sizes, int n_in,
                              void* d_out, int out_size, void* d_ws, size_t ws_size,
                              hipStream_t stream) {
    const float* seq   = (const float*)d_in[0];
    const int*   begin = (const int*)d_in[1];   // int32: harness downcasts jnp.int64
    const int*   end   = (const int*)d_in[2];
    float*       out   = (float*)d_out;
    __half*      ws    = (__half*)d_ws;         // 64*32*4*32 halfs = 512 KB

    dim3 g1(CG * RS, B_);                       // gc fastest -> de-alias batch->CU
    seg_mean_stage1<<<g1, 256, 0, stream>>>(seq, begin, end, ws);
    // (B_*D_)/256 threads-per-block = 256 blocks. R13 had this wrong (1 block).
    seg_mean_stage2<<<256, 256, 0, stream>>>(ws, out);
}